// Round 1
// 698.665 us; speedup vs baseline: 1.3615x; 1.3615x over previous
//
#include <hip/hip_runtime.h>

#define BATCH 16384
#define NNODE 23
#define NF    16
#define HID   128
#define MROWS (BATCH * NNODE)   // 376832
#define MBLK  (MROWS / 16)      // 23552 (exact)

typedef unsigned short u16;
typedef unsigned int   u32;
typedef __attribute__((ext_vector_type(8))) short s16x8;  // 8 bf16
typedef __attribute__((ext_vector_type(4))) float f32x4;

__device__ __forceinline__ float bf2f(u16 v) {
    union { u32 i; float f; } u; u.i = ((u32)v) << 16; return u.f;
}
__device__ __forceinline__ u16 f2bf(float f) {
    union { float f; u32 i; } u; u.f = f;
    return (u16)((u.i + 0x7FFFu + ((u.i >> 16) & 1u)) >> 16);  // RNE
}
// HW packed f32->bf16 (RNE), 2 floats -> 1 u32 {lo16=a, hi16=b}
__device__ __forceinline__ u32 cvtpk(float a, float b) {
    u32 r; asm("v_cvt_pk_bf16_f32 %0, %1, %2" : "=v"(r) : "v"(a), "v"(b));
    return r;
}
__device__ __forceinline__ float sigm(float x) { return 1.0f / (1.0f + __expf(-x)); }
__device__ __forceinline__ float tanh_fast(float x) {
    float e = __expf(2.0f * x);
    return 1.0f - 2.0f / (e + 1.0f);
}
__device__ __forceinline__ float lds1(const void* base, size_t i, int f32) {
    return f32 ? ((const float*)base)[i] : bf2f(((const u16*)base)[i]);
}
__device__ __forceinline__ void st1(void* base, size_t i, int f32, float v) {
    if (f32) ((float*)base)[i] = v;
    else     ((u16*)base)[i]   = f2bf(v);
}
__device__ __forceinline__ s16x8 ldfrag(const void* base, size_t elem_off, int f32) {
    if (f32) {
        const float* f = (const float*)base + elem_off;
        const float4 a = *(const float4*)f;
        const float4 b = *(const float4*)(f + 4);
        return (s16x8){(short)f2bf(a.x), (short)f2bf(a.y), (short)f2bf(a.z), (short)f2bf(a.w),
                       (short)f2bf(b.x), (short)f2bf(b.y), (short)f2bf(b.z), (short)f2bf(b.w)};
    }
    return *(const s16x8*)((const u16*)base + elem_off);
}
__device__ __forceinline__ s16x8 pack_bf16(float4 a, float4 b) {
    union { u32 w[4]; s16x8 v; } u;
    u.w[0] = cvtpk(a.x, a.y); u.w[1] = cvtpk(a.z, a.w);
    u.w[2] = cvtpk(b.x, b.y); u.w[3] = cvtpk(b.z, b.w);
    return u.v;
}
// Per-wave dtype sniff: read 64 u16 from the input. bf16 N(0,1): exponent in
// [0x66,0x90] -> ~0 wild. fp32 misread: even u16s are mantissa slices -> ~26/64
// wild. Threshold 8. All waves read the SAME 64 u16s -> consistent flag.
__device__ __forceinline__ int wave_sniff(const void* p) {
    const u16 v = ((const u16*)p)[threadIdx.x & 63];
    const u32 e = (v >> 7) & 0xFFu;
    const int wild = (e != 0u && (e < 0x66u || e > 0x90u)) ? 1 : 0;
    return __popcll(__ballot(wild)) > 8 ? 1 : 0;
}

// ---------------------------------------------------------------------------
// GCN: spatial = relu( (adj @ x) @ Wg^T + rowsum(adj)*bg ).  One batch per
// WAVE (16384 waves total), wave-private LDS scratch, only 2 cheap barriers
// per block lifetime. Stage1: 46 lanes compute tf=adj@x (8 outs/lane) with
// rowsum fused. Stage2: each lane owns 2 output cols, weights in registers,
// tf read as broadcast float4, packed bf16 store via cvt_pk.
// ---------------------------------------------------------------------------
#define ADJ_OFF 0
#define X_OFF   532
#define TF_OFF  900
#define RS_OFF  1268
#define WSZ     1292

__global__ __launch_bounds__(256, 4) void gcn_kernel(
    const void* __restrict__ x, const void* __restrict__ adj,
    const void* __restrict__ Wg, const void* __restrict__ bg,
    u16* __restrict__ spatial)
{
    __shared__ float sc[4 * WSZ];   // 20.7 KB, per-wave scratch
    const int f32 = wave_sniff(x);
    const int l   = threadIdx.x & 63;
    const int wid = threadIdx.x >> 6;
    const int b   = blockIdx.x * 4 + wid;           // grid is exactly BATCH/4

    float* adjf = &sc[wid * WSZ + ADJ_OFF];
    float* xf   = &sc[wid * WSZ + X_OFF];
    float* tf   = &sc[wid * WSZ + TF_OFF];
    float* rs   = &sc[wid * WSZ + RS_OFF];

    // persistent per-lane weights: output cols c0, c0+1
    const int c0 = 2 * l;
    float wa[NF], wb[NF];
#pragma unroll
    for (int f = 0; f < NF; f++) {
        wa[f] = lds1(Wg, (size_t)c0 * NF + f, f32);
        wb[f] = lds1(Wg, (size_t)(c0 + 1) * NF + f, f32);
    }
    const float bga = lds1(bg, c0, f32);
    const float bgb = lds1(bg, c0 + 1, f32);

    // ---- stage inputs to LDS (wave-coalesced) ----
    if (f32) {
        const float* ap = (const float*)adj + (size_t)b * (NNODE * NNODE);
        for (int i = l; i < NNODE * NNODE; i += 64) adjf[i] = ap[i];
        const float4* xp = (const float4*)((const float*)x + (size_t)b * (NNODE * NF));
        for (int i = l; i < (NNODE * NF) / 4; i += 64) *(float4*)&xf[i * 4] = xp[i];
    } else {
        const u16* ap = (const u16*)adj + (size_t)b * (NNODE * NNODE);
        for (int i = l; i < NNODE * NNODE; i += 64) adjf[i] = bf2f(ap[i]);
        const u16* xp = (const u16*)x + (size_t)b * (NNODE * NF);
        if (l < (NNODE * NF) / 8) {
            s16x8 v = *(const s16x8*)(xp + l * 8);
            float4 t0 = {bf2f((u16)v[0]), bf2f((u16)v[1]), bf2f((u16)v[2]), bf2f((u16)v[3])};
            float4 t1 = {bf2f((u16)v[4]), bf2f((u16)v[5]), bf2f((u16)v[6]), bf2f((u16)v[7])};
            *(float4*)&xf[l * 8]     = t0;
            *(float4*)&xf[l * 8 + 4] = t1;
        }
    }
    __syncthreads();

    // ---- stage1: tf = adj @ x  (+ fused rowsum) ----
    if (l < 2 * NNODE) {                    // 46 active lanes
        const int n  = l >> 1;
        const int f0 = (l & 1) * 8;
        float4 a0 = {0, 0, 0, 0}, a1 = {0, 0, 0, 0};
        float rsum = 0.f;
#pragma unroll
        for (int m = 0; m < NNODE; m++) {
            const float  a  = adjf[n * NNODE + m];
            const float4 x0 = *(const float4*)&xf[m * NF + f0];
            const float4 x1 = *(const float4*)&xf[m * NF + f0 + 4];
            a0.x += a * x0.x; a0.y += a * x0.y; a0.z += a * x0.z; a0.w += a * x0.w;
            a1.x += a * x1.x; a1.y += a * x1.y; a1.z += a * x1.z; a1.w += a * x1.w;
            rsum += a;
        }
        *(float4*)&tf[n * NF + f0]     = a0;
        *(float4*)&tf[n * NF + f0 + 4] = a1;
        if ((l & 1) == 0) rs[n] = rsum;
    }
    __syncthreads();

    // ---- stage2: spatial[n][c0..c0+1] = relu(tf[n] . W + rs[n]*bg) ----
    const u32 sbase = (u32)b * (NNODE * HID);
    u32* sp = (u32*)spatial;
    for (int n = 0; n < NNODE; n++) {
        const float4 t0 = *(const float4*)&tf[n * NF];
        const float4 t1 = *(const float4*)&tf[n * NF + 4];
        const float4 t2 = *(const float4*)&tf[n * NF + 8];
        const float4 t3 = *(const float4*)&tf[n * NF + 12];
        const float  rv = rs[n];
        float a0 = rv * bga;
        float a1 = rv * bgb;
        a0 += t0.x*wa[0]  + t0.y*wa[1]  + t0.z*wa[2]  + t0.w*wa[3];
        a0 += t1.x*wa[4]  + t1.y*wa[5]  + t1.z*wa[6]  + t1.w*wa[7];
        a0 += t2.x*wa[8]  + t2.y*wa[9]  + t2.z*wa[10] + t2.w*wa[11];
        a0 += t3.x*wa[12] + t3.y*wa[13] + t3.z*wa[14] + t3.w*wa[15];
        a1 += t0.x*wb[0]  + t0.y*wb[1]  + t0.z*wb[2]  + t0.w*wb[3];
        a1 += t1.x*wb[4]  + t1.y*wb[5]  + t1.z*wb[6]  + t1.w*wb[7];
        a1 += t2.x*wb[8]  + t2.y*wb[9]  + t2.z*wb[10] + t2.w*wb[11];
        a1 += t3.x*wb[12] + t3.y*wb[13] + t3.z*wb[14] + t3.w*wb[15];
        sp[(sbase + (u32)n * HID + (u32)c0) >> 1] =
            cvtpk(fmaxf(a0, 0.f), fmaxf(a1, 0.f));
    }
}

// ---------------------------------------------------------------------------
// GRU fast path (workspace present, spatial does NOT alias out):
// fully decoupled waves (no barrier), wave = (tile rb, colgroup jt).
// 2048 blocks x 4 waves -> 8192 waves, 1024 per jt, exactly 23 tiles/wave.
// Register double-buffer prefetch of {spatial frags, h frags, epilogue h}.
// h f32->bf16 via v_cvt_pk_bf16_f32 (RNE, bit-identical to manual path).
// r/z accumulators fuse the i- and h-MFMAs (same sum in the gate formula).
// ---------------------------------------------------------------------------
#define LOAD_A(S, H, HP, RB) do {                                              \
    const size_t ar_ = (size_t)((RB) * 16 + n16) * HID + kob;                  \
    _Pragma("unroll")                                                          \
    for (int kt = 0; kt < 4; kt++)                                             \
        S[kt] = *(const s16x8*)&spatial[ar_ + kt * 32];                        \
    if (f32) {                                                                 \
        const float* hp4 = (const float*)h_prev + ar_;                         \
        _Pragma("unroll")                                                      \
        for (int kt = 0; kt < 4; kt++) {                                       \
            H[2*kt]   = *(const float4*)(hp4 + kt * 32);                       \
            H[2*kt+1] = *(const float4*)(hp4 + kt * 32 + 4);                   \
        }                                                                      \
    } else {                                                                   \
        const u16* hb = (const u16*)h_prev + ar_;                              \
        _Pragma("unroll")                                                      \
        for (int kt = 0; kt < 4; kt++)                                         \
            H[2*kt] = *(const float4*)(hb + kt * 32);                          \
    }                                                                          \
    const size_t o_ = (size_t)((RB) * 16 + quad * 4) * HID + c;                \
    if (f32) {                                                                 \
        const float* op = (const float*)h_prev;                                \
        _Pragma("unroll")                                                      \
        for (int r_ = 0; r_ < 4; r_++)                                         \
            HP[r_] = __float_as_uint(op[o_ + (size_t)r_ * HID]);               \
    } else {                                                                   \
        const u16* op = (const u16*)h_prev;                                    \
        _Pragma("unroll")                                                      \
        for (int r_ = 0; r_ < 4; r_++)                                         \
            HP[r_] = (u32)op[o_ + (size_t)r_ * HID];                           \
    }                                                                          \
} while (0)

#define COMPUTE(S, H, HP, RB) do {                                             \
    s16x8 Ah[4];                                                               \
    if (f32) {                                                                 \
        _Pragma("unroll")                                                      \
        for (int kt = 0; kt < 4; kt++) Ah[kt] = pack_bf16(H[2*kt], H[2*kt+1]); \
    } else {                                                                   \
        _Pragma("unroll")                                                      \
        for (int kt = 0; kt < 4; kt++) {                                       \
            union { float4 f; s16x8 s; } u_; u_.f = H[2*kt]; Ah[kt] = u_.s;    \
        }                                                                      \
    }                                                                          \
    f32x4 accr = {0,0,0,0}, accz = {0,0,0,0};                                  \
    f32x4 accni = {0,0,0,0}, accnh = {0,0,0,0};                                \
    _Pragma("unroll")                                                          \
    for (int kt = 0; kt < 4; kt++) {                                           \
        accr  = __builtin_amdgcn_mfma_f32_16x16x32_bf16(S[kt],  Bir[kt], accr, 0,0,0); \
        accr  = __builtin_amdgcn_mfma_f32_16x16x32_bf16(Ah[kt], Bhr[kt], accr, 0,0,0); \
        accz  = __builtin_amdgcn_mfma_f32_16x16x32_bf16(S[kt],  Biz[kt], accz, 0,0,0); \
        accz  = __builtin_amdgcn_mfma_f32_16x16x32_bf16(Ah[kt], Bhz[kt], accz, 0,0,0); \
        accni = __builtin_amdgcn_mfma_f32_16x16x32_bf16(S[kt],  Bin[kt], accni,0,0,0); \
        accnh = __builtin_amdgcn_mfma_f32_16x16x32_bf16(Ah[kt], Bhn[kt], accnh,0,0,0); \
    }                                                                          \
    const size_t o_ = (size_t)((RB) * 16 + quad * 4) * HID + c;                \
    _Pragma("unroll")                                                          \
    for (int reg = 0; reg < 4; reg++) {                                        \
        const float r_  = sigm(accr[reg] + br);                                \
        const float z_  = sigm(accz[reg] + bz);                                \
        const float n_  = tanh_fast(accni[reg] + bin_ + r_ * (accnh[reg] + bhn)); \
        const float hp_ = f32 ? __uint_as_float(HP[reg]) : bf2f((u16)HP[reg]); \
        st1(out, o_ + (size_t)reg * HID, f32, (1.0f - z_) * n_ + z_ * hp_);    \
    }                                                                          \
} while (0)

__global__ __launch_bounds__(256, 2) void gru_fast(
    const u16* __restrict__ spatial, const void* __restrict__ h_prev,
    const void* __restrict__ W_ih, const void* __restrict__ W_hh,
    const void* __restrict__ b_ih, const void* __restrict__ b_hh,
    void* __restrict__ out)
{
    const int f32  = wave_sniff(h_prev);
    const int lane = threadIdx.x & 63;
    const int gw   = blockIdx.x * 4 + (threadIdx.x >> 6);
    const int jt   = gw & 7;             // colgroup: fixed per wave
    const int n16  = lane & 15;
    const int quad = lane >> 4;
    const int c    = jt * 16 + n16;      // gate column 0..127
    const int kob  = quad * 8;

    s16x8 Bir[4], Biz[4], Bin[4], Bhr[4], Bhz[4], Bhn[4];
#pragma unroll
    for (int kt = 0; kt < 4; kt++) {
        const int ko = kt * 32 + kob;
        Bir[kt] = ldfrag(W_ih, (size_t)(c)       * HID + ko, f32);
        Biz[kt] = ldfrag(W_ih, (size_t)(128 + c) * HID + ko, f32);
        Bin[kt] = ldfrag(W_ih, (size_t)(256 + c) * HID + ko, f32);
        Bhr[kt] = ldfrag(W_hh, (size_t)(c)       * HID + ko, f32);
        Bhz[kt] = ldfrag(W_hh, (size_t)(128 + c) * HID + ko, f32);
        Bhn[kt] = ldfrag(W_hh, (size_t)(256 + c) * HID + ko, f32);
    }
    const float br   = lds1(b_ih, c, f32)       + lds1(b_hh, c, f32);
    const float bz   = lds1(b_ih, 128 + c, f32) + lds1(b_hh, 128 + c, f32);
    const float bin_ = lds1(b_ih, 256 + c, f32);
    const float bhn  = lds1(b_hh, 256 + c, f32);

    const int stride = (int)(gridDim.x * 4) >> 3;   // tiles per jt-lane
    int rb = gw >> 3;
    if (rb >= MBLK) return;

    s16x8 S0[4], S1[4];
    float4 H0[8], H1[8];
    u32 P0[4], P1[4];

    LOAD_A(S0, H0, P0, rb);
    int nxt = rb + stride;
    while (true) {
        if (nxt < MBLK) LOAD_A(S1, H1, P1, nxt);    // prefetch depth 1
        COMPUTE(S0, H0, P0, rb);
        rb = nxt; nxt += stride;
        if (rb >= MBLK) break;
        if (nxt < MBLK) LOAD_A(S0, H0, P0, nxt);
        COMPUTE(S1, H1, P1, rb);
        rb = nxt; nxt += stride;
        if (rb >= MBLK) break;
    }
}

// ---------------------------------------------------------------------------
// GRU safe path (workspace too small -> spatial aliases out): previous
// harness-verified kernel, block-coupled with one barrier per tile.
// ---------------------------------------------------------------------------
__global__ __launch_bounds__(512, 2) void gru_safe(
    const u16* __restrict__ spatial, const void* __restrict__ h_prev,
    const void* __restrict__ W_ih, const void* __restrict__ W_hh,
    const void* __restrict__ b_ih, const void* __restrict__ b_hh,
    void* __restrict__ out)
{
    const int f32  = wave_sniff(h_prev);
    const int lane = threadIdx.x & 63;
    const int jt   = threadIdx.x >> 6;
    const int n16  = lane & 15;
    const int quad = lane >> 4;
    const int c    = jt * 16 + n16;
    const int kob  = quad * 8;

    s16x8 Bir[4], Biz[4], Bin[4], Bhr[4], Bhz[4], Bhn[4];
#pragma unroll
    for (int kt = 0; kt < 4; kt++) {
        const int ko = kt * 32 + kob;
        Bir[kt] = ldfrag(W_ih, (size_t)(c)       * HID + ko, f32);
        Biz[kt] = ldfrag(W_ih, (size_t)(128 + c) * HID + ko, f32);
        Bin[kt] = ldfrag(W_ih, (size_t)(256 + c) * HID + ko, f32);
        Bhr[kt] = ldfrag(W_hh, (size_t)(c)       * HID + ko, f32);
        Bhz[kt] = ldfrag(W_hh, (size_t)(128 + c) * HID + ko, f32);
        Bhn[kt] = ldfrag(W_hh, (size_t)(256 + c) * HID + ko, f32);
    }
    const float br   = lds1(b_ih, c, f32)       + lds1(b_hh, c, f32);
    const float bz   = lds1(b_ih, 128 + c, f32) + lds1(b_hh, 128 + c, f32);
    const float bin_ = lds1(b_ih, 256 + c, f32);
    const float bhn  = lds1(b_hh, 256 + c, f32);

    for (int rb = blockIdx.x; rb < MBLK; rb += gridDim.x) {
        const size_t ar = (size_t)(rb * 16 + n16) * HID + kob;
        s16x8 As[4], Ah[4];
#pragma unroll
        for (int kt = 0; kt < 4; kt++) {
            As[kt] = *(const s16x8*)&spatial[ar + kt * 32];
            Ah[kt] = ldfrag(h_prev, ar + kt * 32, f32);
        }

        f32x4 air = {0,0,0,0}, aiz = {0,0,0,0}, ain = {0,0,0,0};
        f32x4 ahr = {0,0,0,0}, ahz = {0,0,0,0}, ahn = {0,0,0,0};
#pragma unroll
        for (int kt = 0; kt < 4; kt++) {
            air = __builtin_amdgcn_mfma_f32_16x16x32_bf16(As[kt], Bir[kt], air, 0, 0, 0);
            ahr = __builtin_amdgcn_mfma_f32_16x16x32_bf16(Ah[kt], Bhr[kt], ahr, 0, 0, 0);
            aiz = __builtin_amdgcn_mfma_f32_16x16x32_bf16(As[kt], Biz[kt], aiz, 0, 0, 0);
            ahz = __builtin_amdgcn_mfma_f32_16x16x32_bf16(Ah[kt], Bhz[kt], ahz, 0, 0, 0);
            ain = __builtin_amdgcn_mfma_f32_16x16x32_bf16(As[kt], Bin[kt], ain, 0, 0, 0);
            ahn = __builtin_amdgcn_mfma_f32_16x16x32_bf16(Ah[kt], Bhn[kt], ahn, 0, 0, 0);
        }

        __syncthreads();   // all spatial reads of rows rb complete before writes

        const int row0 = rb * 16 + quad * 4;
#pragma unroll
        for (int reg = 0; reg < 4; reg++) {
            const size_t o = (size_t)(row0 + reg) * HID + c;
            const float r  = sigm(air[reg] + ahr[reg] + br);
            const float z  = sigm(aiz[reg] + ahz[reg] + bz);
            const float nn = tanh_fast(ain[reg] + bin_ + r * (ahn[reg] + bhn));
            const float hp = lds1(h_prev, o, f32);
            st1(out, o, f32, (1.0f - z) * nn + z * hp);
        }
    }
}

extern "C" void kernel_launch(void* const* d_in, const int* in_sizes, int n_in,
                              void* d_out, int out_size, void* d_ws, size_t ws_size,
                              hipStream_t stream) {
    const void* x      = d_in[0];
    const void* adj    = d_in[1];
    const void* h_prev = d_in[2];
    const void* W_gcn  = d_in[3];
    const void* b_gcn  = d_in[4];
    const void* W_ih   = d_in[5];
    const void* W_hh   = d_in[6];
    const void* b_ih   = d_in[7];
    const void* b_hh   = d_in[8];

    const size_t need = (size_t)MROWS * HID * sizeof(u16);   // 92 MB bf16 spatial
    const bool have_ws = (ws_size >= need);
    u16* spatial = have_ws ? (u16*)d_ws : (u16*)d_out;

    gcn_kernel<<<BATCH / 4, 256, 0, stream>>>(x, adj, W_gcn, b_gcn, spatial);

    if (have_ws)
        gru_fast<<<2048, 256, 0, stream>>>(spatial, h_prev, W_ih, W_hh,
                                           b_ih, b_hh, d_out);
    else
        gru_safe<<<2048, 512, 0, stream>>>(spatial, h_prev, W_ih, W_hh,
                                           b_ih, b_hh, d_out);
}

// Round 2
// 678.647 us; speedup vs baseline: 1.4016x; 1.0295x over previous
//
#include <hip/hip_runtime.h>

#define BATCH 16384
#define NNODE 23
#define NF    16
#define HID   128
#define MROWS (BATCH * NNODE)   // 376832
#define MBLK  (MROWS / 16)      // 23552 (exact)
#define GCN_GRID (BATCH / 4)    // 4096
#define PREP_BLKS 24            // 12 per weight matrix
#define WELEM (3 * HID * HID)   // 49152 elements per weight matrix

typedef unsigned short u16;
typedef unsigned int   u32;
typedef __attribute__((ext_vector_type(8))) short s16x8;  // 8 bf16
typedef __attribute__((ext_vector_type(4))) float f32x4;

__device__ __forceinline__ float bf2f(u16 v) {
    union { u32 i; float f; } u; u.i = ((u32)v) << 16; return u.f;
}
__device__ __forceinline__ u16 f2bf(float f) {
    union { float f; u32 i; } u; u.f = f;
    return (u16)((u.i + 0x7FFFu + ((u.i >> 16) & 1u)) >> 16);  // RNE
}
// HW packed f32->bf16 (RNE), 2 floats -> 1 u32 {lo16=a, hi16=b}
__device__ __forceinline__ u32 cvtpk(float a, float b) {
    u32 r; asm("v_cvt_pk_bf16_f32 %0, %1, %2" : "=v"(r) : "v"(a), "v"(b));
    return r;
}
__device__ __forceinline__ float sigm(float x) { return 1.0f / (1.0f + __expf(-x)); }
__device__ __forceinline__ float tanh_fast(float x) {
    float e = __expf(2.0f * x);
    return 1.0f - 2.0f / (e + 1.0f);
}
__device__ __forceinline__ float lds1(const void* base, size_t i, int f32) {
    return f32 ? ((const float*)base)[i] : bf2f(((const u16*)base)[i]);
}
__device__ __forceinline__ void st1(void* base, size_t i, int f32, float v) {
    if (f32) ((float*)base)[i] = v;
    else     ((u16*)base)[i]   = f2bf(v);
}
__device__ __forceinline__ s16x8 ldfrag(const void* base, size_t elem_off, int f32) {
    if (f32) {
        const float* f = (const float*)base + elem_off;
        const float4 a = *(const float4*)f;
        const float4 b = *(const float4*)(f + 4);
        return (s16x8){(short)f2bf(a.x), (short)f2bf(a.y), (short)f2bf(a.z), (short)f2bf(a.w),
                       (short)f2bf(b.x), (short)f2bf(b.y), (short)f2bf(b.z), (short)f2bf(b.w)};
    }
    return *(const s16x8*)((const u16*)base + elem_off);
}
__device__ __forceinline__ s16x8 pack_bf16(float4 a, float4 b) {
    union { u32 w[4]; s16x8 v; } u;
    u.w[0] = cvtpk(a.x, a.y); u.w[1] = cvtpk(a.z, a.w);
    u.w[2] = cvtpk(b.x, b.y); u.w[3] = cvtpk(b.z, b.w);
    return u.v;
}
// Per-wave dtype sniff (works for N(0,1) activations and uniform small
// weights alike): bf16 exponents land in [0x66,0x90] -> ~0 wild; fp32
// misread makes even u16s mantissa slices -> ~40% wild. Threshold 8/64.
__device__ __forceinline__ int wave_sniff(const void* p) {
    const u16 v = ((const u16*)p)[threadIdx.x & 63];
    const u32 e = (v >> 7) & 0xFFu;
    const int wild = (e != 0u && (e < 0x66u || e > 0x90u)) ? 1 : 0;
    return __popcll(__ballot(wild)) > 8 ? 1 : 0;
}

// ---------------------------------------------------------------------------
// GCN (+ weight prep): blocks [0, GCN_GRID) compute
//   spatial = relu( (adj @ x) @ Wg^T + rowsum(adj)*bg )   (one batch per wave)
// blocks [GCN_GRID, GCN_GRID+24) convert W_ih / W_hh to bf16 in workspace
// (removes all per-tile weight conversion from the GRU hot loop).
// ---------------------------------------------------------------------------
#define ADJ_OFF 0
#define X_OFF   532
#define TF_OFF  900
#define RS_OFF  1268
#define WSZ     1292

__global__ __launch_bounds__(256, 4) void gcn_kernel(
    const void* __restrict__ x, const void* __restrict__ adj,
    const void* __restrict__ Wg, const void* __restrict__ bg,
    u16* __restrict__ spatial,
    const void* __restrict__ W_ih, const void* __restrict__ W_hh,
    u16* __restrict__ wih_b, u16* __restrict__ whh_b)
{
    __shared__ float sc[4 * WSZ];   // 20.7 KB, per-wave scratch

    if (blockIdx.x >= GCN_GRID) {
        // ---- weight prep path ----
        if (!wih_b) return;
        const int pb = blockIdx.x - GCN_GRID;        // 0..23
        const void* src = (pb < 12) ? W_ih : W_hh;
        u16*        dst = (pb < 12) ? wih_b : whh_b;
        const int   p   = (pb < 12) ? pb : pb - 12;  // 0..11
        const int wf32  = wave_sniff(src);
        const int base  = (p * 256 + (int)threadIdx.x) * 16;  // 16 elems/thread
        u32* d = (u32*)(dst + base);
        if (wf32) {
            const float4* s = (const float4*)((const float*)src + base);
            const float4 v0 = s[0], v1 = s[1], v2 = s[2], v3 = s[3];
            d[0] = cvtpk(v0.x, v0.y); d[1] = cvtpk(v0.z, v0.w);
            d[2] = cvtpk(v1.x, v1.y); d[3] = cvtpk(v1.z, v1.w);
            d[4] = cvtpk(v2.x, v2.y); d[5] = cvtpk(v2.z, v2.w);
            d[6] = cvtpk(v3.x, v3.y); d[7] = cvtpk(v3.z, v3.w);
        } else {
            const u32* s = (const u32*)((const u16*)src + base);
#pragma unroll
            for (int i = 0; i < 8; i++) d[i] = s[i];
        }
        return;
    }

    const int f32 = wave_sniff(x);
    const int l   = threadIdx.x & 63;
    const int wid = threadIdx.x >> 6;
    const int b   = blockIdx.x * 4 + wid;

    float* adjf = &sc[wid * WSZ + ADJ_OFF];
    float* xf   = &sc[wid * WSZ + X_OFF];
    float* tf   = &sc[wid * WSZ + TF_OFF];
    float* rs   = &sc[wid * WSZ + RS_OFF];

    // persistent per-lane weights: output cols c0, c0+1
    const int c0 = 2 * l;
    float wa[NF], wb[NF];
#pragma unroll
    for (int f = 0; f < NF; f++) {
        wa[f] = lds1(Wg, (size_t)c0 * NF + f, f32);
        wb[f] = lds1(Wg, (size_t)(c0 + 1) * NF + f, f32);
    }
    const float bga = lds1(bg, c0, f32);
    const float bgb = lds1(bg, c0 + 1, f32);

    // ---- stage inputs to LDS (wave-coalesced) ----
    if (f32) {
        const float* ap = (const float*)adj + (size_t)b * (NNODE * NNODE);
        for (int i = l; i < NNODE * NNODE; i += 64) adjf[i] = ap[i];
        const float4* xp = (const float4*)((const float*)x + (size_t)b * (NNODE * NF));
        for (int i = l; i < (NNODE * NF) / 4; i += 64) *(float4*)&xf[i * 4] = xp[i];
    } else {
        const u16* ap = (const u16*)adj + (size_t)b * (NNODE * NNODE);
        for (int i = l; i < NNODE * NNODE; i += 64) adjf[i] = bf2f(ap[i]);
        const u16* xp = (const u16*)x + (size_t)b * (NNODE * NF);
        if (l < (NNODE * NF) / 8) {
            s16x8 v = *(const s16x8*)(xp + l * 8);
            float4 t0 = {bf2f((u16)v[0]), bf2f((u16)v[1]), bf2f((u16)v[2]), bf2f((u16)v[3])};
            float4 t1 = {bf2f((u16)v[4]), bf2f((u16)v[5]), bf2f((u16)v[6]), bf2f((u16)v[7])};
            *(float4*)&xf[l * 8]     = t0;
            *(float4*)&xf[l * 8 + 4] = t1;
        }
    }
    __syncthreads();

    // ---- stage1: tf = adj @ x  (+ fused rowsum) ----
    if (l < 2 * NNODE) {
        const int n  = l >> 1;
        const int f0 = (l & 1) * 8;
        float4 a0 = {0, 0, 0, 0}, a1 = {0, 0, 0, 0};
        float rsum = 0.f;
#pragma unroll
        for (int m = 0; m < NNODE; m++) {
            const float  a  = adjf[n * NNODE + m];
            const float4 x0 = *(const float4*)&xf[m * NF + f0];
            const float4 x1 = *(const float4*)&xf[m * NF + f0 + 4];
            a0.x += a * x0.x; a0.y += a * x0.y; a0.z += a * x0.z; a0.w += a * x0.w;
            a1.x += a * x1.x; a1.y += a * x1.y; a1.z += a * x1.z; a1.w += a * x1.w;
            rsum += a;
        }
        *(float4*)&tf[n * NF + f0]     = a0;
        *(float4*)&tf[n * NF + f0 + 4] = a1;
        if ((l & 1) == 0) rs[n] = rsum;
    }
    __syncthreads();

    // ---- stage2: spatial[n][c0..c0+1] = relu(tf[n] . W + rs[n]*bg) ----
    const u32 sbase = (u32)b * (NNODE * HID);
    u32* sp = (u32*)spatial;
    for (int n = 0; n < NNODE; n++) {
        const float4 t0 = *(const float4*)&tf[n * NF];
        const float4 t1 = *(const float4*)&tf[n * NF + 4];
        const float4 t2 = *(const float4*)&tf[n * NF + 8];
        const float4 t3 = *(const float4*)&tf[n * NF + 12];
        const float  rv = rs[n];
        float a0 = rv * bga;
        float a1 = rv * bgb;
        a0 += t0.x*wa[0]  + t0.y*wa[1]  + t0.z*wa[2]  + t0.w*wa[3];
        a0 += t1.x*wa[4]  + t1.y*wa[5]  + t1.z*wa[6]  + t1.w*wa[7];
        a0 += t2.x*wa[8]  + t2.y*wa[9]  + t2.z*wa[10] + t2.w*wa[11];
        a0 += t3.x*wa[12] + t3.y*wa[13] + t3.z*wa[14] + t3.w*wa[15];
        a1 += t0.x*wb[0]  + t0.y*wb[1]  + t0.z*wb[2]  + t0.w*wb[3];
        a1 += t1.x*wb[4]  + t1.y*wb[5]  + t1.z*wb[6]  + t1.w*wb[7];
        a1 += t2.x*wb[8]  + t2.y*wb[9]  + t2.z*wb[10] + t2.w*wb[11];
        a1 += t3.x*wb[12] + t3.y*wb[13] + t3.z*wb[14] + t3.w*wb[15];
        sp[(sbase + (u32)n * HID + (u32)c0) >> 1] =
            cvtpk(fmaxf(a0, 0.f), fmaxf(a1, 0.f));
    }
}

// ---------------------------------------------------------------------------
// GRU fast path: decoupled waves (no barrier), wave = (tile rb, colgroup jt).
// B fragments are plain s16x8 loads from pre-converted bf16 weights ->
// loop-invariant, nothing to rematerialize; state ~235 VGPR fits the
// launch_bounds(256,2) 256-reg cap, 2 waves/SIMD, depth-1 prefetch.
// ---------------------------------------------------------------------------
#define LOAD_A(S, H, RB) do {                                                  \
    const size_t ar_ = (size_t)((RB) * 16 + n16) * HID + kob;                  \
    _Pragma("unroll")                                                          \
    for (int kt = 0; kt < 4; kt++)                                             \
        S[kt] = *(const s16x8*)&spatial[ar_ + kt * 32];                        \
    if (f32) {                                                                 \
        const float* hp4 = (const float*)h_prev + ar_;                         \
        _Pragma("unroll")                                                      \
        for (int kt = 0; kt < 4; kt++) {                                       \
            H[2*kt]   = *(const float4*)(hp4 + kt * 32);                       \
            H[2*kt+1] = *(const float4*)(hp4 + kt * 32 + 4);                   \
        }                                                                      \
    } else {                                                                   \
        const u16* hb = (const u16*)h_prev + ar_;                              \
        _Pragma("unroll")                                                      \
        for (int kt = 0; kt < 4; kt++)                                         \
            H[2*kt] = *(const float4*)(hb + kt * 32);                          \
    }                                                                          \
} while (0)

#define COMPUTE(S, H, RB) do {                                                 \
    const size_t o_ = (size_t)((RB) * 16 + quad * 4) * HID + c;                \
    float hp_[4];  /* L1-hot: same rows this wave just loaded for H */         \
    _Pragma("unroll")                                                          \
    for (int r_ = 0; r_ < 4; r_++)                                             \
        hp_[r_] = lds1(h_prev, o_ + (size_t)r_ * HID, f32);                    \
    s16x8 Ah[4];                                                               \
    if (f32) {                                                                 \
        _Pragma("unroll")                                                      \
        for (int kt = 0; kt < 4; kt++) Ah[kt] = pack_bf16(H[2*kt], H[2*kt+1]); \
    } else {                                                                   \
        _Pragma("unroll")                                                      \
        for (int kt = 0; kt < 4; kt++) {                                       \
            union { float4 f; s16x8 s; } u_; u_.f = H[2*kt]; Ah[kt] = u_.s;    \
        }                                                                      \
    }                                                                          \
    f32x4 accr = {0,0,0,0}, accz = {0,0,0,0};                                  \
    f32x4 accni = {0,0,0,0}, accnh = {0,0,0,0};                                \
    _Pragma("unroll")                                                          \
    for (int kt = 0; kt < 4; kt++) {                                           \
        accr  = __builtin_amdgcn_mfma_f32_16x16x32_bf16(S[kt],  Bir[kt], accr, 0,0,0); \
        accr  = __builtin_amdgcn_mfma_f32_16x16x32_bf16(Ah[kt], Bhr[kt], accr, 0,0,0); \
        accz  = __builtin_amdgcn_mfma_f32_16x16x32_bf16(S[kt],  Biz[kt], accz, 0,0,0); \
        accz  = __builtin_amdgcn_mfma_f32_16x16x32_bf16(Ah[kt], Bhz[kt], accz, 0,0,0); \
        accni = __builtin_amdgcn_mfma_f32_16x16x32_bf16(S[kt],  Bin[kt], accni,0,0,0); \
        accnh = __builtin_amdgcn_mfma_f32_16x16x32_bf16(Ah[kt], Bhn[kt], accnh,0,0,0); \
    }                                                                          \
    _Pragma("unroll")                                                          \
    for (int reg = 0; reg < 4; reg++) {                                        \
        const float r_ = sigm(accr[reg] + br);                                 \
        const float z_ = sigm(accz[reg] + bz);                                 \
        const float n_ = tanh_fast(accni[reg] + bin_ + r_ * (accnh[reg] + bhn)); \
        st1(out, o_ + (size_t)reg * HID, f32, (1.0f - z_) * n_ + z_ * hp_[reg]); \
    }                                                                          \
} while (0)

__global__ __launch_bounds__(256, 2) void gru_fast(
    const u16* __restrict__ spatial, const void* __restrict__ h_prev,
    const u16* __restrict__ wih_b, const u16* __restrict__ whh_b,
    const void* __restrict__ b_ih, const void* __restrict__ b_hh,
    void* __restrict__ out)
{
    const int f32  = wave_sniff(h_prev);
    const int lane = threadIdx.x & 63;
    const int gw   = blockIdx.x * 4 + (threadIdx.x >> 6);
    const int jt   = gw & 7;             // colgroup: fixed per wave
    const int n16  = lane & 15;
    const int quad = lane >> 4;
    const int c    = jt * 16 + n16;      // gate column 0..127
    const int kob  = quad * 8;

    // persistent B fragments: plain bf16 loads (no conversion, no remat bait)
    s16x8 Bir[4], Biz[4], Bin[4], Bhr[4], Bhz[4], Bhn[4];
#pragma unroll
    for (int kt = 0; kt < 4; kt++) {
        const int ko = kt * 32 + kob;
        Bir[kt] = *(const s16x8*)&wih_b[(size_t)(c)       * HID + ko];
        Biz[kt] = *(const s16x8*)&wih_b[(size_t)(128 + c) * HID + ko];
        Bin[kt] = *(const s16x8*)&wih_b[(size_t)(256 + c) * HID + ko];
        Bhr[kt] = *(const s16x8*)&whh_b[(size_t)(c)       * HID + ko];
        Bhz[kt] = *(const s16x8*)&whh_b[(size_t)(128 + c) * HID + ko];
        Bhn[kt] = *(const s16x8*)&whh_b[(size_t)(256 + c) * HID + ko];
    }
    const float br   = lds1(b_ih, c, f32)       + lds1(b_hh, c, f32);
    const float bz   = lds1(b_ih, 128 + c, f32) + lds1(b_hh, 128 + c, f32);
    const float bin_ = lds1(b_ih, 256 + c, f32);
    const float bhn  = lds1(b_hh, 256 + c, f32);

    const int stride = (int)(gridDim.x * 4) >> 3;   // row-wave count per jt
    int rb = gw >> 3;
    if (rb >= MBLK) return;

    s16x8 S0[4], S1[4];
    float4 H0[8], H1[8];

    LOAD_A(S0, H0, rb);
    int nxt = rb + stride;
    while (true) {
        if (nxt < MBLK) LOAD_A(S1, H1, nxt);    // prefetch depth 1
        COMPUTE(S0, H0, rb);
        rb = nxt; nxt += stride;
        if (rb >= MBLK) break;
        if (nxt < MBLK) LOAD_A(S0, H0, nxt);
        COMPUTE(S1, H1, rb);
        rb = nxt; nxt += stride;
        if (rb >= MBLK) break;
    }
}

// ---------------------------------------------------------------------------
// GRU safe path (workspace too small): block-coupled, one barrier per tile,
// f32 weights converted in-register (slow but correct for any ws_size).
// ---------------------------------------------------------------------------
__global__ __launch_bounds__(512, 2) void gru_safe(
    const u16* __restrict__ spatial, const void* __restrict__ h_prev,
    const void* __restrict__ W_ih, const void* __restrict__ W_hh,
    const void* __restrict__ b_ih, const void* __restrict__ b_hh,
    void* __restrict__ out)
{
    const int f32  = wave_sniff(h_prev);
    const int lane = threadIdx.x & 63;
    const int jt   = threadIdx.x >> 6;
    const int n16  = lane & 15;
    const int quad = lane >> 4;
    const int c    = jt * 16 + n16;
    const int kob  = quad * 8;

    s16x8 Bir[4], Biz[4], Bin[4], Bhr[4], Bhz[4], Bhn[4];
#pragma unroll
    for (int kt = 0; kt < 4; kt++) {
        const int ko = kt * 32 + kob;
        Bir[kt] = ldfrag(W_ih, (size_t)(c)       * HID + ko, f32);
        Biz[kt] = ldfrag(W_ih, (size_t)(128 + c) * HID + ko, f32);
        Bin[kt] = ldfrag(W_ih, (size_t)(256 + c) * HID + ko, f32);
        Bhr[kt] = ldfrag(W_hh, (size_t)(c)       * HID + ko, f32);
        Bhz[kt] = ldfrag(W_hh, (size_t)(128 + c) * HID + ko, f32);
        Bhn[kt] = ldfrag(W_hh, (size_t)(256 + c) * HID + ko, f32);
    }
    const float br   = lds1(b_ih, c, f32)       + lds1(b_hh, c, f32);
    const float bz   = lds1(b_ih, 128 + c, f32) + lds1(b_hh, 128 + c, f32);
    const float bin_ = lds1(b_ih, 256 + c, f32);
    const float bhn  = lds1(b_hh, 256 + c, f32);

    for (int rb = blockIdx.x; rb < MBLK; rb += gridDim.x) {
        const size_t ar = (size_t)(rb * 16 + n16) * HID + kob;
        s16x8 As[4], Ah[4];
#pragma unroll
        for (int kt = 0; kt < 4; kt++) {
            As[kt] = *(const s16x8*)&spatial[ar + kt * 32];
            Ah[kt] = ldfrag(h_prev, ar + kt * 32, f32);
        }

        f32x4 air = {0,0,0,0}, aiz = {0,0,0,0}, ain = {0,0,0,0};
        f32x4 ahr = {0,0,0,0}, ahz = {0,0,0,0}, ahn = {0,0,0,0};
#pragma unroll
        for (int kt = 0; kt < 4; kt++) {
            air = __builtin_amdgcn_mfma_f32_16x16x32_bf16(As[kt], Bir[kt], air, 0, 0, 0);
            ahr = __builtin_amdgcn_mfma_f32_16x16x32_bf16(Ah[kt], Bhr[kt], ahr, 0, 0, 0);
            aiz = __builtin_amdgcn_mfma_f32_16x16x32_bf16(As[kt], Biz[kt], aiz, 0, 0, 0);
            ahz = __builtin_amdgcn_mfma_f32_16x16x32_bf16(Ah[kt], Bhz[kt], ahz, 0, 0, 0);
            ain = __builtin_amdgcn_mfma_f32_16x16x32_bf16(As[kt], Bin[kt], ain, 0, 0, 0);
            ahn = __builtin_amdgcn_mfma_f32_16x16x32_bf16(Ah[kt], Bhn[kt], ahn, 0, 0, 0);
        }

        __syncthreads();   // all spatial reads of rows rb complete before writes

        const int row0 = rb * 16 + quad * 4;
#pragma unroll
        for (int reg = 0; reg < 4; reg++) {
            const size_t o = (size_t)(row0 + reg) * HID + c;
            const float r  = sigm(air[reg] + ahr[reg] + br);
            const float z  = sigm(aiz[reg] + ahz[reg] + bz);
            const float nn = tanh_fast(ain[reg] + bin_ + r * (ahn[reg] + bhn));
            const float hp = lds1(h_prev, o, f32);
            st1(out, o, f32, (1.0f - z) * nn + z * hp);
        }
    }
}

extern "C" void kernel_launch(void* const* d_in, const int* in_sizes, int n_in,
                              void* d_out, int out_size, void* d_ws, size_t ws_size,
                              hipStream_t stream) {
    const void* x      = d_in[0];
    const void* adj    = d_in[1];
    const void* h_prev = d_in[2];
    const void* W_gcn  = d_in[3];
    const void* b_gcn  = d_in[4];
    const void* W_ih   = d_in[5];
    const void* W_hh   = d_in[6];
    const void* b_ih   = d_in[7];
    const void* b_hh   = d_in[8];

    const size_t need   = (size_t)MROWS * HID * sizeof(u16);   // 92 MB bf16 spatial
    const size_t wbytes = (size_t)WELEM * sizeof(u16);         // 96 KB per matrix
    const bool have_ws = (ws_size >= need);
    const bool have_w  = (ws_size >= need + 2 * wbytes);

    u16* spatial = have_ws ? (u16*)d_ws : (u16*)d_out;
    u16* wih_b   = have_w ? (u16*)((char*)d_ws + need) : nullptr;
    u16* whh_b   = have_w ? (u16*)((char*)d_ws + need + wbytes) : nullptr;

    gcn_kernel<<<GCN_GRID + (have_w ? PREP_BLKS : 0), 256, 0, stream>>>(
        x, adj, W_gcn, b_gcn, spatial, W_ih, W_hh, wih_b, whh_b);

    if (have_w)
        gru_fast<<<2048, 256, 0, stream>>>(spatial, h_prev, wih_b, whh_b,
                                           b_ih, b_hh, d_out);
    else
        gru_safe<<<2048, 512, 0, stream>>>(spatial, h_prev, W_ih, W_hh,
                                           b_ih, b_hh, d_out);
}